// Round 12
// baseline (645.253 us; speedup 1.0000x reference)
//
#include <hip/hip_runtime.h>
#include <hip/hip_bf16.h>

// Problem constants (MoE grouped FFN, uniform groups)
#define NE 32      // experts
#define HD 2048    // hidden
#define ID 1024    // intermediate
#define GT 1024    // tokens per expert (T/E = 32768/32)

#define BK 64

typedef __attribute__((ext_vector_type(8))) __bf16 bf16x8;
typedef __attribute__((ext_vector_type(4))) float  f32x4;

__device__ __forceinline__ __bf16 f2b(float f) { return (__bf16)f; }

__device__ __forceinline__ bf16x8 pack8(const f32x4 a, const f32x4 b) {
  bf16x8 v;
  v[0] = f2b(a[0]); v[1] = f2b(a[1]); v[2] = f2b(a[2]); v[3] = f2b(a[3]);
  v[4] = f2b(b[0]); v[5] = f2b(b[1]); v[6] = f2b(b[2]); v[7] = f2b(b[3]);
  return v;
}

#define SBAR() __builtin_amdgcn_s_barrier()
#define LGKM0() asm volatile("s_waitcnt lgkmcnt(0)" ::: "memory")

// ---------------------------------------------------------------------------
// Prepass: x (f32, T*H) -> x_bf16 in ws. Memory-bound streaming.
// ---------------------------------------------------------------------------
__global__ __launch_bounds__(256)
void cvt_x_bf16(const float* __restrict__ x, __bf16* __restrict__ xb) {
  size_t i = ((size_t)blockIdx.x * 256 + threadIdx.x) * 8;
  f32x4 a = *reinterpret_cast<const f32x4*>(x + i);
  f32x4 b = *reinterpret_cast<const f32x4*>(x + i + 4);
  *reinterpret_cast<bf16x8*>(xb + i) = pack8(a, b);
}

// ---------------------------------------------------------------------------
// Kernel 1 (256-tile, 8-PHASE): gate_up = x_e @ w13_e ; h = silu(gate)*up
// BM=256, gate/up each 128 wide. 512 threads = 8 waves (2x4); wave owns
// 128 rows x 32 cols of both gate and up (acc = 128 f32).
// Per K-tile: 4 phases of {ds_read quarter ∥ one staging slice -> barrier ->
// lgkmcnt(0) -> setprio(1) -> 16 MFMA -> setprio(0) -> barrier}  (T3; m196).
// Correctness is barrier-count-independent (reads p, writes p^1, reg deps
// compiler-enforced; loads stay in flight ~3 phases -> never vmcnt(0)).
// Carried verbatim (counter-verified): bf16-A staging, f32-B column-walk+cvt,
// XOR swizzles, XCD-chunked remap, setprio, lgkm-only barriers.
// ---------------------------------------------------------------------------
__global__ __launch_bounds__(512, 2)
void moe_gemm1_swiglu_bA(const __bf16* __restrict__ xb,
                         const float* __restrict__ w13,
                         __bf16* __restrict__ h) {
  __shared__ __bf16 As[2][256][BK];
  __shared__ __bf16 Bg[2][128][BK];
  __shared__ __bf16 Bu[2][128][BK];

  const int t = threadIdx.x;
  const int bid  = blockIdx.x;
  const int work = (bid & 7) * 128 + (bid >> 3);
  const int e    = work >> 5;
  const int rem  = work & 31;
  const int n0   = (rem >> 2) * 128;
  const int m0   = (rem & 3) * 256;

  const __bf16* xA = xb + (size_t)(e * GT + m0) * HD;
  const float*  wB = w13 + (size_t)e * HD * (2 * ID);

  const int wid = t >> 6, lane = t & 63;
  const int wm = wid >> 2, wn = wid & 3;
  const int fr = lane & 15, fq = lane >> 4;

  const int tb = t & 255;
  const int nq = tb & 31;
  const int ko = tb >> 5;
  const int bcol = (t < 256 ? 0 : ID) + n0 + nq * 4;
  __bf16 (*Bm)[128][BK] = (t < 256) ? Bg : Bu;

  f32x4 accg[8][2];
  f32x4 accu[8][2];
#pragma unroll
  for (int i = 0; i < 8; ++i)
#pragma unroll
    for (int j = 0; j < 2; ++j) { accg[i][j] = 0.f; accu[i][j] = 0.f; }

  bf16x8 raa[4];
  f32x4 rb[8];

#define LOAD_A1(K0)                                                            \
  do {                                                                         \
    _Pragma("unroll")                                                          \
    for (int i = 0; i < 4; ++i) {                                              \
      int id = i * 512 + t;                                                    \
      int koA = id & 7, m = id >> 3;                                           \
      raa[i] = *reinterpret_cast<const bf16x8*>(xA + (size_t)m * HD + (K0) + koA * 8); \
    }                                                                          \
  } while (0)

#define LOAD_B1(K0)                                                            \
  do {                                                                         \
    const float* pb = wB + (size_t)((K0) + ko * 8) * (2 * ID) + bcol;          \
    _Pragma("unroll")                                                          \
    for (int j = 0; j < 8; ++j)                                                \
      rb[j] = *reinterpret_cast<const f32x4*>(pb + (size_t)j * (2 * ID));      \
  } while (0)

#define STORE_A1(P)                                                            \
  do {                                                                         \
    _Pragma("unroll")                                                          \
    for (int i = 0; i < 4; ++i) {                                              \
      int id = i * 512 + t;                                                    \
      int koA = id & 7, m = id >> 3;                                           \
      *reinterpret_cast<bf16x8*>(&As[P][m][(koA ^ (m & 7)) * 8]) = raa[i];     \
    }                                                                          \
  } while (0)

#define STORE_B1(P)                                                            \
  do {                                                                         \
    _Pragma("unroll")                                                          \
    for (int c = 0; c < 4; ++c) {                                              \
      int row = nq * 4 + c;                                                    \
      int slot = (ko ^ ((row >> 1) & 7)) * 8;                                  \
      bf16x8 v;                                                                \
      _Pragma("unroll")                                                        \
      for (int j = 0; j < 8; ++j) v[j] = f2b(rb[j][c]);                        \
      *reinterpret_cast<bf16x8*>(&Bm[P][row][slot]) = v;                       \
    }                                                                          \
  } while (0)

  // prologue: stage tile0 -> buf0; prefetch tile1 regs
  LOAD_A1(0);
  LOAD_B1(0);
  STORE_A1(0);
  STORE_B1(0);
  LOAD_A1(BK);
  LOAD_B1(BK);
  LGKM0();
  SBAR();

  for (int k0 = 0, p = 0; k0 < HD; k0 += BK, p ^= 1) {
    const bool stg = (k0 + BK < HD);
    const bool pre = (k0 + 2 * BK < HD);
    bf16x8 af[8], bgf[2], buv[2];

    // ---- P1: reads(af kb0, bg kb0) | MFMA g/kb0 ----
#pragma unroll
    for (int mi = 0; mi < 8; ++mi) {
      int row = wm * 128 + mi * 16 + fr;
      af[mi] = *reinterpret_cast<const bf16x8*>(&As[p][row][(fq ^ (row & 7)) * 8]);
    }
#pragma unroll
    for (int ni = 0; ni < 2; ++ni) {
      int row = wn * 32 + ni * 16 + fr;
      bgf[ni] = *reinterpret_cast<const bf16x8*>(&Bg[p][row][(fq ^ ((row >> 1) & 7)) * 8]);
    }
    SBAR(); LGKM0();
    __builtin_amdgcn_s_setprio(1);
#pragma unroll
    for (int mi = 0; mi < 8; ++mi)
#pragma unroll
      for (int ni = 0; ni < 2; ++ni)
        accg[mi][ni] = __builtin_amdgcn_mfma_f32_16x16x32_bf16(af[mi], bgf[ni], accg[mi][ni], 0, 0, 0);
    __builtin_amdgcn_s_setprio(0);
    SBAR();

    // ---- P2: reads(bu kb0) | STORE-A(p^1) + issue A(k+2) | MFMA u/kb0 ----
#pragma unroll
    for (int ni = 0; ni < 2; ++ni) {
      int row = wn * 32 + ni * 16 + fr;
      buv[ni] = *reinterpret_cast<const bf16x8*>(&Bu[p][row][(fq ^ ((row >> 1) & 7)) * 8]);
    }
    if (stg) STORE_A1(p ^ 1);
    if (pre) LOAD_A1(k0 + 2 * BK);
    SBAR(); LGKM0();
    __builtin_amdgcn_s_setprio(1);
#pragma unroll
    for (int mi = 0; mi < 8; ++mi)
#pragma unroll
      for (int ni = 0; ni < 2; ++ni)
        accu[mi][ni] = __builtin_amdgcn_mfma_f32_16x16x32_bf16(af[mi], buv[ni], accu[mi][ni], 0, 0, 0);
    __builtin_amdgcn_s_setprio(0);
    SBAR();

    // ---- P3: reads(af kb4, bg kb4) | STORE-B(p^1) | MFMA g/kb4 ----
#pragma unroll
    for (int mi = 0; mi < 8; ++mi) {
      int row = wm * 128 + mi * 16 + fr;
      af[mi] = *reinterpret_cast<const bf16x8*>(&As[p][row][((fq + 4) ^ (row & 7)) * 8]);
    }
#pragma unroll
    for (int ni = 0; ni < 2; ++ni) {
      int row = wn * 32 + ni * 16 + fr;
      bgf[ni] = *reinterpret_cast<const bf16x8*>(&Bg[p][row][((fq + 4) ^ ((row >> 1) & 7)) * 8]);
    }
    if (stg) STORE_B1(p ^ 1);
    SBAR(); LGKM0();
    __builtin_amdgcn_s_setprio(1);
#pragma unroll
    for (int mi = 0; mi < 8; ++mi)
#pragma unroll
      for (int ni = 0; ni < 2; ++ni)
        accg[mi][ni] = __builtin_amdgcn_mfma_f32_16x16x32_bf16(af[mi], bgf[ni], accg[mi][ni], 0, 0, 0);
    __builtin_amdgcn_s_setprio(0);
    SBAR();

    // ---- P4: reads(bu kb4) | issue B(k+2) | MFMA u/kb4 ----
#pragma unroll
    for (int ni = 0; ni < 2; ++ni) {
      int row = wn * 32 + ni * 16 + fr;
      buv[ni] = *reinterpret_cast<const bf16x8*>(&Bu[p][row][((fq + 4) ^ ((row >> 1) & 7)) * 8]);
    }
    if (pre) LOAD_B1(k0 + 2 * BK);
    SBAR(); LGKM0();
    __builtin_amdgcn_s_setprio(1);
#pragma unroll
    for (int mi = 0; mi < 8; ++mi)
#pragma unroll
      for (int ni = 0; ni < 2; ++ni)
        accu[mi][ni] = __builtin_amdgcn_mfma_f32_16x16x32_bf16(af[mi], buv[ni], accu[mi][ni], 0, 0, 0);
    __builtin_amdgcn_s_setprio(0);
    SBAR();
  }
#undef LOAD_A1
#undef LOAD_B1
#undef STORE_A1
#undef STORE_B1

  // ---- epilogue: SwiGLU (in-wave), write h (bf16) ----
#pragma unroll
  for (int mi = 0; mi < 8; ++mi)
#pragma unroll
    for (int ni = 0; ni < 2; ++ni)
#pragma unroll
      for (int j = 0; j < 4; ++j) {
        int row = m0 + wm * 128 + mi * 16 + fq * 4 + j;
        int col = n0 + wn * 32 + ni * 16 + fr;
        float g = accg[mi][ni][j];
        float u = accu[mi][ni][j];
        float s = g / (1.f + __expf(-g));
        h[(size_t)(e * GT + row) * ID + col] = f2b(s * u);
      }
}

// ---------------------------------------------------------------------------
// Kernel 1 fallback (f32 A, R7 structure) — used only if ws_size too small.
// ---------------------------------------------------------------------------
__global__ __launch_bounds__(256, 2)
void moe_gemm1_swiglu(const float* __restrict__ x,
                      const float* __restrict__ w13,
                      __bf16* __restrict__ h) {
  __shared__ __bf16 As[2][128][BK];
  __shared__ __bf16 Bg[2][64][BK];
  __shared__ __bf16 Bu[2][64][BK];

  const int t  = threadIdx.x;
  const int e  = blockIdx.z;
  const int m0 = blockIdx.y * 128;
  const int n0 = blockIdx.x * 64;

  const float* xA = x   + (size_t)(e * GT + m0) * HD;
  const float* wB = w13 + (size_t)e * HD * (2 * ID);

  const int wid = t >> 6, lane = t & 63;
  const int wm = wid >> 1, wn = wid & 1;
  const int fr = lane & 15, fq = lane >> 4;

  const int tb = t & 127;
  const int nq = tb & 15;
  const int ko = tb >> 4;
  const int bcol = (t < 128 ? 0 : ID) + n0 + nq * 4;
  __bf16 (*Bm)[64][BK] = (t < 128) ? Bg : Bu;

  f32x4 accg[4][2];
  f32x4 accu[4][2];
#pragma unroll
  for (int i = 0; i < 4; ++i)
#pragma unroll
    for (int j = 0; j < 2; ++j) { accg[i][j] = 0.f; accu[i][j] = 0.f; }

  f32x4 ra[4][2];
  f32x4 rb[8];

#define LOAD_TILE1(K0)                                                         \
  do {                                                                         \
    _Pragma("unroll")                                                          \
    for (int i = 0; i < 4; ++i) {                                              \
      int id = i * 256 + t;                                                    \
      int r = id >> 3, oc = id & 7;                                            \
      const float* src = xA + (size_t)r * HD + (K0) + oc * 8;                  \
      ra[i][0] = *reinterpret_cast<const f32x4*>(src);                         \
      ra[i][1] = *reinterpret_cast<const f32x4*>(src + 4);                     \
    }                                                                          \
    const float* pb = wB + (size_t)((K0) + ko * 8) * (2 * ID) + bcol;          \
    _Pragma("unroll")                                                          \
    for (int j = 0; j < 8; ++j)                                                \
      rb[j] = *reinterpret_cast<const f32x4*>(pb + (size_t)j * (2 * ID));      \
  } while (0)

#define STORE_TILE1(P)                                                         \
  do {                                                                         \
    _Pragma("unroll")                                                          \
    for (int i = 0; i < 4; ++i) {                                              \
      int id = i * 256 + t;                                                    \
      int r = id >> 3, oc = id & 7;                                            \
      *reinterpret_cast<bf16x8*>(&As[P][r][(oc ^ (r & 7)) * 8]) =              \
          pack8(ra[i][0], ra[i][1]);                                           \
    }                                                                          \
    _Pragma("unroll")                                                          \
    for (int c = 0; c < 4; ++c) {                                              \
      int row = nq * 4 + c;                                                    \
      int slot = (ko ^ ((row >> 1) & 7)) * 8;                                  \
      bf16x8 v;                                                                \
      _Pragma("unroll")                                                        \
      for (int j = 0; j < 8; ++j) v[j] = f2b(rb[j][c]);                        \
      *reinterpret_cast<bf16x8*>(&Bm[P][row][slot]) = v;                       \
    }                                                                          \
  } while (0)

#define MFMA_HALF1(P, KB)                                                      \
  do {                                                                         \
    bf16x8 af[4], bgf[2], buf2[2];                                             \
    _Pragma("unroll")                                                          \
    for (int mi = 0; mi < 4; ++mi) {                                           \
      int row = wm * 64 + mi * 16 + fr;                                        \
      int oct = (fq + (KB)) ^ (row & 7);                                       \
      af[mi] = *reinterpret_cast<const bf16x8*>(&As[P][row][oct * 8]);         \
    }                                                                          \
    _Pragma("unroll")                                                          \
    for (int ni = 0; ni < 2; ++ni) {                                           \
      int row = wn * 32 + ni * 16 + fr;                                        \
      int oct = (fq + (KB)) ^ ((row >> 1) & 7);                                \
      bgf[ni]  = *reinterpret_cast<const bf16x8*>(&Bg[P][row][oct * 8]);       \
      buf2[ni] = *reinterpret_cast<const bf16x8*>(&Bu[P][row][oct * 8]);       \
    }                                                                          \
    __builtin_amdgcn_s_setprio(1);                                             \
    _Pragma("unroll")                                                          \
    for (int mi = 0; mi < 4; ++mi)                                             \
      _Pragma("unroll")                                                        \
      for (int ni = 0; ni < 2; ++ni) {                                         \
        accg[mi][ni] = __builtin_amdgcn_mfma_f32_16x16x32_bf16(                \
            af[mi], bgf[ni], accg[mi][ni], 0, 0, 0);                           \
        accu[mi][ni] = __builtin_amdgcn_mfma_f32_16x16x32_bf16(                \
            af[mi], buf2[ni], accu[mi][ni], 0, 0, 0);                          \
      }                                                                        \
    __builtin_amdgcn_s_setprio(0);                                             \
  } while (0)

  LOAD_TILE1(0);
  STORE_TILE1(0);
  LOAD_TILE1(BK);
  LGKM0();
  SBAR();

  for (int k0 = 0, p = 0; k0 < HD; k0 += BK, p ^= 1) {
    MFMA_HALF1(p, 0);
    if (k0 + BK < HD) STORE_TILE1(p ^ 1);
    MFMA_HALF1(p, 4);
    if (k0 + 2 * BK < HD) LOAD_TILE1(k0 + 2 * BK);
    LGKM0();
    SBAR();
  }
#undef LOAD_TILE1
#undef STORE_TILE1
#undef MFMA_HALF1

#pragma unroll
  for (int mi = 0; mi < 4; ++mi)
#pragma unroll
    for (int ni = 0; ni < 2; ++ni)
#pragma unroll
      for (int j = 0; j < 4; ++j) {
        int row = m0 + wm * 64 + mi * 16 + fq * 4 + j;
        int col = n0 + wn * 32 + ni * 16 + fr;
        float g = accg[mi][ni][j];
        float u = accu[mi][ni][j];
        float s = g / (1.f + __expf(-g));
        h[(size_t)(e * GT + row) * ID + col] = f2b(s * u);
      }
}

// ---------------------------------------------------------------------------
// Kernel 2 (256x256 tile, 8-PHASE): out = h @ w2_e
// 512 threads = 8 waves (2x4); wave owns 128 rows x 64 cols (acc 128 f32).
// Same phase schedule as gemm1: quarters = kb(2) x ni-half(2).
// ---------------------------------------------------------------------------
__global__ __launch_bounds__(512, 2)
void moe_gemm2(const __bf16* __restrict__ h,
               const float* __restrict__ w2,
               float* __restrict__ out) {
  __shared__ __bf16 As[2][256][BK];
  __shared__ __bf16 Bs[2][256][BK];

  const int t = threadIdx.x;
  const int bid  = blockIdx.x;
  const int work = (bid & 7) * 128 + (bid >> 3);
  const int e    = work >> 5;
  const int rem  = work & 31;
  const int n0   = (rem >> 2) * 256;
  const int m0   = (rem & 3) * 256;

  const __bf16* hA = h  + (size_t)(e * GT + m0) * ID;
  const float*  wB = w2 + (size_t)e * ID * HD;

  const int wid = t >> 6, lane = t & 63;
  const int wm = wid >> 2, wn = wid & 3;
  const int fr = lane & 15, fq = lane >> 4;

  const int nq = t & 63;
  const int ko = t >> 6;

  f32x4 acc[8][4];
#pragma unroll
  for (int i = 0; i < 8; ++i)
#pragma unroll
    for (int j = 0; j < 4; ++j) acc[i][j] = 0.f;

  bf16x8 raa[4];
  f32x4 rb[8];

#define LOAD_A2(K0)                                                            \
  do {                                                                         \
    _Pragma("unroll")                                                          \
    for (int i = 0; i < 4; ++i) {                                              \
      int id = i * 512 + t;                                                    \
      int koA = id & 7, m = id >> 3;                                           \
      raa[i] = *reinterpret_cast<const bf16x8*>(hA + (size_t)m * ID + (K0) + koA * 8); \
    }                                                                          \
  } while (0)

#define LOAD_B2(K0)                                                            \
  do {                                                                         \
    const float* pg = wB + (size_t)((K0) + ko * 8) * HD + (n0 + nq * 4);       \
    _Pragma("unroll")                                                          \
    for (int j = 0; j < 8; ++j)                                                \
      rb[j] = *reinterpret_cast<const f32x4*>(pg + (size_t)j * HD);            \
  } while (0)

#define STORE_A2(P)                                                            \
  do {                                                                         \
    _Pragma("unroll")                                                          \
    for (int i = 0; i < 4; ++i) {                                              \
      int id = i * 512 + t;                                                    \
      int koA = id & 7, m = id >> 3;                                           \
      *reinterpret_cast<bf16x8*>(&As[P][m][(koA ^ (m & 7)) * 8]) = raa[i];     \
    }                                                                          \
  } while (0)

#define STORE_B2(P)                                                            \
  do {                                                                         \
    _Pragma("unroll")                                                          \
    for (int c = 0; c < 4; ++c) {                                              \
      int row = nq * 4 + c;                                                    \
      int slot = (ko ^ ((row >> 1) & 7)) * 8;                                  \
      bf16x8 v;                                                                \
      _Pragma("unroll")                                                        \
      for (int j = 0; j < 8; ++j) v[j] = f2b(rb[j][c]);                        \
      *reinterpret_cast<bf16x8*>(&Bs[P][row][slot]) = v;                       \
    }                                                                          \
  } while (0)

  LOAD_A2(0);
  LOAD_B2(0);
  STORE_A2(0);
  STORE_B2(0);
  LOAD_A2(BK);
  LOAD_B2(BK);
  LGKM0();
  SBAR();

  for (int k0 = 0, p = 0; k0 < ID; k0 += BK, p ^= 1) {
    const bool stg = (k0 + BK < ID);
    const bool pre = (k0 + 2 * BK < ID);
    bf16x8 af[8], bf[2];

    // ---- P1: reads(af kb0, b01 kb0) | MFMA ni01/kb0 ----
#pragma unroll
    for (int mi = 0; mi < 8; ++mi) {
      int row = wm * 128 + mi * 16 + fr;
      af[mi] = *reinterpret_cast<const bf16x8*>(&As[p][row][(fq ^ (row & 7)) * 8]);
    }
#pragma unroll
    for (int ni = 0; ni < 2; ++ni) {
      int row = wn * 64 + ni * 16 + fr;
      bf[ni] = *reinterpret_cast<const bf16x8*>(&Bs[p][row][(fq ^ ((row >> 1) & 7)) * 8]);
    }
    SBAR(); LGKM0();
    __builtin_amdgcn_s_setprio(1);
#pragma unroll
    for (int mi = 0; mi < 8; ++mi)
#pragma unroll
      for (int ni = 0; ni < 2; ++ni)
        acc[mi][ni] = __builtin_amdgcn_mfma_f32_16x16x32_bf16(af[mi], bf[ni], acc[mi][ni], 0, 0, 0);
    __builtin_amdgcn_s_setprio(0);
    SBAR();

    // ---- P2: reads(b23 kb0) | STORE-A + issue A(k+2) | MFMA ni23/kb0 ----
#pragma unroll
    for (int ni = 0; ni < 2; ++ni) {
      int row = wn * 64 + (ni + 2) * 16 + fr;
      bf[ni] = *reinterpret_cast<const bf16x8*>(&Bs[p][row][(fq ^ ((row >> 1) & 7)) * 8]);
    }
    if (stg) STORE_A2(p ^ 1);
    if (pre) LOAD_A2(k0 + 2 * BK);
    SBAR(); LGKM0();
    __builtin_amdgcn_s_setprio(1);
#pragma unroll
    for (int mi = 0; mi < 8; ++mi)
#pragma unroll
      for (int ni = 0; ni < 2; ++ni)
        acc[mi][ni + 2] = __builtin_amdgcn_mfma_f32_16x16x32_bf16(af[mi], bf[ni], acc[mi][ni + 2], 0, 0, 0);
    __builtin_amdgcn_s_setprio(0);
    SBAR();

    // ---- P3: reads(af kb4, b01 kb4) | STORE-B | MFMA ni01/kb4 ----
#pragma unroll
    for (int mi = 0; mi < 8; ++mi) {
      int row = wm * 128 + mi * 16 + fr;
      af[mi] = *reinterpret_cast<const bf16x8*>(&As[p][row][((fq + 4) ^ (row & 7)) * 8]);
    }
#pragma unroll
    for (int ni = 0; ni < 2; ++ni) {
      int row = wn * 64 + ni * 16 + fr;
      bf[ni] = *reinterpret_cast<const bf16x8*>(&Bs[p][row][((fq + 4) ^ ((row >> 1) & 7)) * 8]);
    }
    if (stg) STORE_B2(p ^ 1);
    SBAR(); LGKM0();
    __builtin_amdgcn_s_setprio(1);
#pragma unroll
    for (int mi = 0; mi < 8; ++mi)
#pragma unroll
      for (int ni = 0; ni < 2; ++ni)
        acc[mi][ni] = __builtin_amdgcn_mfma_f32_16x16x32_bf16(af[mi], bf[ni], acc[mi][ni], 0, 0, 0);
    __builtin_amdgcn_s_setprio(0);
    SBAR();

    // ---- P4: reads(b23 kb4) | issue B(k+2) | MFMA ni23/kb4 ----
#pragma unroll
    for (int ni = 0; ni < 2; ++ni) {
      int row = wn * 64 + (ni + 2) * 16 + fr;
      bf[ni] = *reinterpret_cast<const bf16x8*>(&Bs[p][row][((fq + 4) ^ ((row >> 1) & 7)) * 8]);
    }
    if (pre) LOAD_B2(k0 + 2 * BK);
    SBAR(); LGKM0();
    __builtin_amdgcn_s_setprio(1);
#pragma unroll
    for (int mi = 0; mi < 8; ++mi)
#pragma unroll
      for (int ni = 0; ni < 2; ++ni)
        acc[mi][ni + 2] = __builtin_amdgcn_mfma_f32_16x16x32_bf16(af[mi], bf[ni], acc[mi][ni + 2], 0, 0, 0);
    __builtin_amdgcn_s_setprio(0);
    SBAR();
  }
#undef LOAD_A2
#undef LOAD_B2
#undef STORE_A2
#undef STORE_B2

#pragma unroll
  for (int mi = 0; mi < 8; ++mi)
#pragma unroll
    for (int ni = 0; ni < 4; ++ni)
#pragma unroll
      for (int j = 0; j < 4; ++j) {
        int row = m0 + wm * 128 + mi * 16 + fq * 4 + j;
        int col = n0 + wn * 64 + ni * 16 + fr;
        out[(size_t)(e * GT + row) * HD + col] = acc[mi][ni][j];
      }
}

extern "C" void kernel_launch(void* const* d_in, const int* in_sizes, int n_in,
                              void* d_out, int out_size, void* d_ws, size_t ws_size,
                              hipStream_t stream) {
  const float* x   = (const float*)d_in[0];
  const float* w13 = (const float*)d_in[1];
  const float* w2  = (const float*)d_in[2];
  float* out = (float*)d_out;

  // ws layout: h [0, 64 MiB) ; x_bf16 [64 MiB, 192 MiB)
  const size_t H_BYTES  = (size_t)GT * NE * ID * sizeof(__bf16);   // 64 MiB
  const size_t XB_BYTES = (size_t)GT * NE * HD * sizeof(__bf16);   // 128 MiB
  __bf16* h  = (__bf16*)d_ws;
  __bf16* xb = (__bf16*)((char*)d_ws + H_BYTES);

  if (ws_size >= H_BYTES + XB_BYTES) {
    cvt_x_bf16<<<dim3((GT * NE * (HD / 8)) / 256), dim3(256), 0, stream>>>(x, xb);
    moe_gemm1_swiglu_bA<<<dim3(1024), dim3(512), 0, stream>>>(xb, w13, h);
  } else {
    moe_gemm1_swiglu<<<dim3(ID / 64, GT / 128, NE), dim3(256), 0, stream>>>(x, w13, h);
  }
  moe_gemm2<<<dim3(1024), dim3(512), 0, stream>>>(h, w2, out);
}

// Round 13
// 616.930 us; speedup vs baseline: 1.0459x; 1.0459x over previous
//
#include <hip/hip_runtime.h>
#include <hip/hip_bf16.h>

// Problem constants (MoE grouped FFN, uniform groups)
#define NE 32      // experts
#define HD 2048    // hidden
#define ID 1024    // intermediate
#define GT 1024    // tokens per expert (T/E = 32768/32)

#define BK 64

typedef __attribute__((ext_vector_type(8)))  __bf16 bf16x8;
typedef __attribute__((ext_vector_type(4)))  float  f32x4;
typedef __attribute__((ext_vector_type(16))) float  f32x16;

__device__ __forceinline__ __bf16 f2b(float f) { return (__bf16)f; }

__device__ __forceinline__ bf16x8 pack8(const f32x4 a, const f32x4 b) {
  bf16x8 v;
  v[0] = f2b(a[0]); v[1] = f2b(a[1]); v[2] = f2b(a[2]); v[3] = f2b(a[3]);
  v[4] = f2b(b[0]); v[5] = f2b(b[1]); v[6] = f2b(b[2]); v[7] = f2b(b[3]);
  return v;
}

#define SBAR() __builtin_amdgcn_s_barrier()
#define LGKM0() asm volatile("s_waitcnt lgkmcnt(0)" ::: "memory")

// ---------------------------------------------------------------------------
// Prepass: x (f32, T*H) -> x_bf16 in ws. Memory-bound streaming.
// ---------------------------------------------------------------------------
__global__ __launch_bounds__(256)
void cvt_x_bf16(const float* __restrict__ x, __bf16* __restrict__ xb) {
  size_t i = ((size_t)blockIdx.x * 256 + threadIdx.x) * 8;
  f32x4 a = *reinterpret_cast<const f32x4*>(x + i);
  f32x4 b = *reinterpret_cast<const f32x4*>(x + i + 4);
  *reinterpret_cast<bf16x8*>(xb + i) = pack8(a, b);
}

// ---------------------------------------------------------------------------
// Kernel 1 (256-tile, R11 2-phase loop, 32x32x16 MFMA):
// gate_up = x_e @ w13_e ; h = silu(gate)*up.
// 512 threads = 8 waves (2x4); wave owns 128 rows x 32 cols of both gate and
// up as 4x 32x32 tiles each (acc = 2x4x f32x16 = 128 f32).
// 32x32x16 halves MFMA instruction count at same LDS traffic (+15% pipe
// ceiling, fewer issue slots contending with DS/VALU).
// Fragment layout: A lane l -> row l&31, k=(l>>5)*8+j ; C/D col=lane&31,
// row=(reg&3)+8*(reg>>2)+4*(lane>>5) (m74/m101-verified).
// Staging/swizzle/remap verbatim from R11 (counter-verified).
// ---------------------------------------------------------------------------
__global__ __launch_bounds__(512, 2)
void moe_gemm1_swiglu_bA(const __bf16* __restrict__ xb,
                         const float* __restrict__ w13,
                         __bf16* __restrict__ h) {
  __shared__ __bf16 As[2][256][BK];
  __shared__ __bf16 Bg[2][128][BK];
  __shared__ __bf16 Bu[2][128][BK];

  const int t = threadIdx.x;
  const int bid  = blockIdx.x;
  const int work = (bid & 7) * 128 + (bid >> 3);
  const int e    = work >> 5;
  const int rem  = work & 31;
  const int n0   = (rem >> 2) * 128;
  const int m0   = (rem & 3) * 256;

  const __bf16* xA = xb + (size_t)(e * GT + m0) * HD;
  const float*  wB = w13 + (size_t)e * HD * (2 * ID);

  const int wid = t >> 6, lane = t & 63;
  const int wm = wid >> 2, wn = wid & 3;   // 2x4 waves: 128 rows x 32 cols
  const int fr = lane & 31, fq = lane >> 5; // 32x32 fragment coords

  const int tb = t & 255;
  const int nq = tb & 31;
  const int ko = tb >> 5;
  const int bcol = (t < 256 ? 0 : ID) + n0 + nq * 4;
  __bf16 (*Bm)[128][BK] = (t < 256) ? Bg : Bu;

  f32x16 accg[4];
  f32x16 accu[4];
#pragma unroll
  for (int i = 0; i < 4; ++i) { accg[i] = 0.f; accu[i] = 0.f; }

  bf16x8 raa[4];
  f32x4 rb[8];

#define LOAD_TILE1(K0)                                                         \
  do {                                                                         \
    _Pragma("unroll")                                                          \
    for (int i = 0; i < 4; ++i) {                                              \
      int id = i * 512 + t;                                                    \
      int koA = id & 7, m = id >> 3;                                           \
      raa[i] = *reinterpret_cast<const bf16x8*>(xA + (size_t)m * HD + (K0) + koA * 8); \
    }                                                                          \
    const float* pb = wB + (size_t)((K0) + ko * 8) * (2 * ID) + bcol;          \
    _Pragma("unroll")                                                          \
    for (int j = 0; j < 8; ++j)                                                \
      rb[j] = *reinterpret_cast<const f32x4*>(pb + (size_t)j * (2 * ID));      \
  } while (0)

#define STORE_TILE1(P)                                                         \
  do {                                                                         \
    _Pragma("unroll")                                                          \
    for (int i = 0; i < 4; ++i) {                                              \
      int id = i * 512 + t;                                                    \
      int koA = id & 7, m = id >> 3;                                           \
      *reinterpret_cast<bf16x8*>(&As[P][m][(koA ^ (m & 7)) * 8]) = raa[i];     \
    }                                                                          \
    _Pragma("unroll")                                                          \
    for (int c = 0; c < 4; ++c) {                                              \
      int row = nq * 4 + c;                                                    \
      int slot = (ko ^ ((row >> 1) & 7)) * 8;                                  \
      bf16x8 v;                                                                \
      _Pragma("unroll")                                                        \
      for (int j = 0; j < 8; ++j) v[j] = f2b(rb[j][c]);                        \
      *reinterpret_cast<bf16x8*>(&Bm[P][row][slot]) = v;                       \
    }                                                                          \
  } while (0)

// One half-K-tile: ks = KS0, KS0+1 (K=16 each). 8 A-reads, 4 B-reads, 16 MFMA.
#define MFMA_HALF1(P, KS0)                                                     \
  do {                                                                         \
    bf16x8 af[4][2], bgf[2], buv[2];                                           \
    _Pragma("unroll")                                                          \
    for (int mi = 0; mi < 4; ++mi) {                                           \
      int row = wm * 128 + mi * 32 + fr;                                       \
      _Pragma("unroll")                                                        \
      for (int s = 0; s < 2; ++s) {                                            \
        int oct = (fq + 2 * ((KS0) + s)) ^ (row & 7);                          \
        af[mi][s] = *reinterpret_cast<const bf16x8*>(&As[P][row][oct * 8]);    \
      }                                                                        \
    }                                                                          \
    {                                                                          \
      int brow = wn * 32 + fr;                                                 \
      _Pragma("unroll")                                                        \
      for (int s = 0; s < 2; ++s) {                                            \
        int oct = (fq + 2 * ((KS0) + s)) ^ ((brow >> 1) & 7);                  \
        bgf[s] = *reinterpret_cast<const bf16x8*>(&Bg[P][brow][oct * 8]);      \
        buv[s] = *reinterpret_cast<const bf16x8*>(&Bu[P][brow][oct * 8]);      \
      }                                                                        \
    }                                                                          \
    __builtin_amdgcn_s_setprio(1);                                             \
    _Pragma("unroll")                                                          \
    for (int mi = 0; mi < 4; ++mi)                                             \
      _Pragma("unroll")                                                        \
      for (int s = 0; s < 2; ++s) {                                            \
        accg[mi] = __builtin_amdgcn_mfma_f32_32x32x16_bf16(                    \
            af[mi][s], bgf[s], accg[mi], 0, 0, 0);                             \
        accu[mi] = __builtin_amdgcn_mfma_f32_32x32x16_bf16(                    \
            af[mi][s], buv[s], accu[mi], 0, 0, 0);                             \
      }                                                                        \
    __builtin_amdgcn_s_setprio(0);                                             \
  } while (0)

  LOAD_TILE1(0);
  STORE_TILE1(0);
  LOAD_TILE1(BK);
  LGKM0();
  SBAR();

  for (int k0 = 0, p = 0; k0 < HD; k0 += BK, p ^= 1) {
    MFMA_HALF1(p, 0);
    if (k0 + BK < HD) STORE_TILE1(p ^ 1);      // overlaps MFMA (other buffer)
    MFMA_HALF1(p, 2);
    if (k0 + 2 * BK < HD) LOAD_TILE1(k0 + 2 * BK);
    LGKM0();
    SBAR();
  }
#undef LOAD_TILE1
#undef STORE_TILE1
#undef MFMA_HALF1

  // ---- epilogue: SwiGLU (in-wave), write h (bf16) ----
#pragma unroll
  for (int mi = 0; mi < 4; ++mi)
#pragma unroll
    for (int r = 0; r < 16; ++r) {
      int row = m0 + wm * 128 + mi * 32 + fq * 4 + (r & 3) + 8 * (r >> 2);
      int col = n0 + wn * 32 + fr;
      float g = accg[mi][r];
      float u = accu[mi][r];
      float s = g / (1.f + __expf(-g));
      h[(size_t)(e * GT + row) * ID + col] = f2b(s * u);
    }
}

// ---------------------------------------------------------------------------
// Kernel 1 fallback (f32 A, R7 structure) — used only if ws_size too small.
// ---------------------------------------------------------------------------
__global__ __launch_bounds__(256, 2)
void moe_gemm1_swiglu(const float* __restrict__ x,
                      const float* __restrict__ w13,
                      __bf16* __restrict__ h) {
  __shared__ __bf16 As[2][128][BK];
  __shared__ __bf16 Bg[2][64][BK];
  __shared__ __bf16 Bu[2][64][BK];

  const int t  = threadIdx.x;
  const int e  = blockIdx.z;
  const int m0 = blockIdx.y * 128;
  const int n0 = blockIdx.x * 64;

  const float* xA = x   + (size_t)(e * GT + m0) * HD;
  const float* wB = w13 + (size_t)e * HD * (2 * ID);

  const int wid = t >> 6, lane = t & 63;
  const int wm = wid >> 1, wn = wid & 1;
  const int fr = lane & 15, fq = lane >> 4;

  const int tb = t & 127;
  const int nq = tb & 15;
  const int ko = tb >> 4;
  const int bcol = (t < 128 ? 0 : ID) + n0 + nq * 4;
  __bf16 (*Bm)[64][BK] = (t < 128) ? Bg : Bu;

  f32x4 accg[4][2];
  f32x4 accu[4][2];
#pragma unroll
  for (int i = 0; i < 4; ++i)
#pragma unroll
    for (int j = 0; j < 2; ++j) { accg[i][j] = 0.f; accu[i][j] = 0.f; }

  f32x4 ra[4][2];
  f32x4 rb[8];

#define LOAD_TILE1(K0)                                                         \
  do {                                                                         \
    _Pragma("unroll")                                                          \
    for (int i = 0; i < 4; ++i) {                                              \
      int id = i * 256 + t;                                                    \
      int r = id >> 3, oc = id & 7;                                            \
      const float* src = xA + (size_t)r * HD + (K0) + oc * 8;                  \
      ra[i][0] = *reinterpret_cast<const f32x4*>(src);                         \
      ra[i][1] = *reinterpret_cast<const f32x4*>(src + 4);                     \
    }                                                                          \
    const float* pb = wB + (size_t)((K0) + ko * 8) * (2 * ID) + bcol;          \
    _Pragma("unroll")                                                          \
    for (int j = 0; j < 8; ++j)                                                \
      rb[j] = *reinterpret_cast<const f32x4*>(pb + (size_t)j * (2 * ID));      \
  } while (0)

#define STORE_TILE1(P)                                                         \
  do {                                                                         \
    _Pragma("unroll")                                                          \
    for (int i = 0; i < 4; ++i) {                                              \
      int id = i * 256 + t;                                                    \
      int r = id >> 3, oc = id & 7;                                            \
      *reinterpret_cast<bf16x8*>(&As[P][r][(oc ^ (r & 7)) * 8]) =              \
          pack8(ra[i][0], ra[i][1]);                                           \
    }                                                                          \
    _Pragma("unroll")                                                          \
    for (int c = 0; c < 4; ++c) {                                              \
      int row = nq * 4 + c;                                                    \
      int slot = (ko ^ ((row >> 1) & 7)) * 8;                                  \
      bf16x8 v;                                                                \
      _Pragma("unroll")                                                        \
      for (int j = 0; j < 8; ++j) v[j] = f2b(rb[j][c]);                        \
      *reinterpret_cast<bf16x8*>(&Bm[P][row][slot]) = v;                       \
    }                                                                          \
  } while (0)

#define MFMA_HALF1(P, KB)                                                      \
  do {                                                                         \
    bf16x8 af[4], bgf[2], buf2[2];                                             \
    _Pragma("unroll")                                                          \
    for (int mi = 0; mi < 4; ++mi) {                                           \
      int row = wm * 64 + mi * 16 + fr;                                        \
      int oct = (fq + (KB)) ^ (row & 7);                                       \
      af[mi] = *reinterpret_cast<const bf16x8*>(&As[P][row][oct * 8]);         \
    }                                                                          \
    _Pragma("unroll")                                                          \
    for (int ni = 0; ni < 2; ++ni) {                                           \
      int row = wn * 32 + ni * 16 + fr;                                        \
      int oct = (fq + (KB)) ^ ((row >> 1) & 7);                                \
      bgf[ni]  = *reinterpret_cast<const bf16x8*>(&Bg[P][row][oct * 8]);       \
      buf2[ni] = *reinterpret_cast<const bf16x8*>(&Bu[P][row][oct * 8]);       \
    }                                                                          \
    __builtin_amdgcn_s_setprio(1);                                             \
    _Pragma("unroll")                                                          \
    for (int mi = 0; mi < 4; ++mi)                                             \
      _Pragma("unroll")                                                        \
      for (int ni = 0; ni < 2; ++ni) {                                         \
        accg[mi][ni] = __builtin_amdgcn_mfma_f32_16x16x32_bf16(                \
            af[mi], bgf[ni], accg[mi][ni], 0, 0, 0);                           \
        accu[mi][ni] = __builtin_amdgcn_mfma_f32_16x16x32_bf16(                \
            af[mi], buf2[ni], accu[mi][ni], 0, 0, 0);                          \
      }                                                                        \
    __builtin_amdgcn_s_setprio(0);                                             \
  } while (0)

  LOAD_TILE1(0);
  STORE_TILE1(0);
  LOAD_TILE1(BK);
  LGKM0();
  SBAR();

  for (int k0 = 0, p = 0; k0 < HD; k0 += BK, p ^= 1) {
    MFMA_HALF1(p, 0);
    if (k0 + BK < HD) STORE_TILE1(p ^ 1);
    MFMA_HALF1(p, 4);
    if (k0 + 2 * BK < HD) LOAD_TILE1(k0 + 2 * BK);
    LGKM0();
    SBAR();
  }
#undef LOAD_TILE1
#undef STORE_TILE1
#undef MFMA_HALF1

#pragma unroll
  for (int mi = 0; mi < 4; ++mi)
#pragma unroll
    for (int ni = 0; ni < 2; ++ni)
#pragma unroll
      for (int j = 0; j < 4; ++j) {
        int row = m0 + wm * 64 + mi * 16 + fq * 4 + j;
        int col = n0 + wn * 32 + ni * 16 + fr;
        float g = accg[mi][ni][j];
        float u = accu[mi][ni][j];
        float s = g / (1.f + __expf(-g));
        h[(size_t)(e * GT + row) * ID + col] = f2b(s * u);
      }
}

// ---------------------------------------------------------------------------
// Kernel 2 (256x256 tile, R11 2-phase loop, 32x32x16 MFMA): out = h @ w2_e
// 512 threads = 8 waves (2x4); wave owns 128 rows x 64 cols as 4x2 tiles of
// 32x32 (acc = 8x f32x16 = 128 f32).
// ---------------------------------------------------------------------------
__global__ __launch_bounds__(512, 2)
void moe_gemm2(const __bf16* __restrict__ h,
               const float* __restrict__ w2,
               float* __restrict__ out) {
  __shared__ __bf16 As[2][256][BK];
  __shared__ __bf16 Bs[2][256][BK];

  const int t = threadIdx.x;
  const int bid  = blockIdx.x;
  const int work = (bid & 7) * 128 + (bid >> 3);
  const int e    = work >> 5;
  const int rem  = work & 31;
  const int n0   = (rem >> 2) * 256;
  const int m0   = (rem & 3) * 256;

  const __bf16* hA = h  + (size_t)(e * GT + m0) * ID;
  const float*  wB = w2 + (size_t)e * ID * HD;

  const int wid = t >> 6, lane = t & 63;
  const int wm = wid >> 2, wn = wid & 3;   // 2x4 waves: 128 rows x 64 cols
  const int fr = lane & 31, fq = lane >> 5;

  const int nq = t & 63;
  const int ko = t >> 6;

  f32x16 acc[4][2];
#pragma unroll
  for (int i = 0; i < 4; ++i)
#pragma unroll
    for (int j = 0; j < 2; ++j) acc[i][j] = 0.f;

  bf16x8 raa[4];
  f32x4 rb[8];

#define LOAD_TILE2(K0)                                                         \
  do {                                                                         \
    _Pragma("unroll")                                                          \
    for (int i = 0; i < 4; ++i) {                                              \
      int id = i * 512 + t;                                                    \
      int koA = id & 7, m = id >> 3;                                           \
      raa[i] = *reinterpret_cast<const bf16x8*>(hA + (size_t)m * ID + (K0) + koA * 8); \
    }                                                                          \
    const float* pg = wB + (size_t)((K0) + ko * 8) * HD + (n0 + nq * 4);       \
    _Pragma("unroll")                                                          \
    for (int j = 0; j < 8; ++j)                                                \
      rb[j] = *reinterpret_cast<const f32x4*>(pg + (size_t)j * HD);            \
  } while (0)

#define STORE_TILE2(P)                                                         \
  do {                                                                         \
    _Pragma("unroll")                                                          \
    for (int i = 0; i < 4; ++i) {                                              \
      int id = i * 512 + t;                                                    \
      int koA = id & 7, m = id >> 3;                                           \
      *reinterpret_cast<bf16x8*>(&As[P][m][(koA ^ (m & 7)) * 8]) = raa[i];     \
    }                                                                          \
    _Pragma("unroll")                                                          \
    for (int c = 0; c < 4; ++c) {                                              \
      int row = nq * 4 + c;                                                    \
      int slot = (ko ^ ((row >> 1) & 7)) * 8;                                  \
      bf16x8 v;                                                                \
      _Pragma("unroll")                                                        \
      for (int j = 0; j < 8; ++j) v[j] = f2b(rb[j][c]);                        \
      *reinterpret_cast<bf16x8*>(&Bs[P][row][slot]) = v;                       \
    }                                                                          \
  } while (0)

#define MFMA_HALF2(P, KS0)                                                     \
  do {                                                                         \
    bf16x8 af[4][2], bf2[2][2];                                                \
    _Pragma("unroll")                                                          \
    for (int mi = 0; mi < 4; ++mi) {                                           \
      int row = wm * 128 + mi * 32 + fr;                                       \
      _Pragma("unroll")                                                        \
      for (int s = 0; s < 2; ++s) {                                            \
        int oct = (fq + 2 * ((KS0) + s)) ^ (row & 7);                          \
        af[mi][s] = *reinterpret_cast<const bf16x8*>(&As[P][row][oct * 8]);    \
      }                                                                        \
    }                                                                          \
    _Pragma("unroll")                                                          \
    for (int nj = 0; nj < 2; ++nj) {                                           \
      int brow = wn * 64 + nj * 32 + fr;                                       \
      _Pragma("unroll")                                                        \
      for (int s = 0; s < 2; ++s) {                                            \
        int oct = (fq + 2 * ((KS0) + s)) ^ ((brow >> 1) & 7);                  \
        bf2[nj][s] = *reinterpret_cast<const bf16x8*>(&Bs[P][brow][oct * 8]);  \
      }                                                                        \
    }                                                                          \
    __builtin_amdgcn_s_setprio(1);                                             \
    _Pragma("unroll")                                                          \
    for (int mi = 0; mi < 4; ++mi)                                             \
      _Pragma("unroll")                                                        \
      for (int nj = 0; nj < 2; ++nj)                                           \
        _Pragma("unroll")                                                      \
        for (int s = 0; s < 2; ++s)                                            \
          acc[mi][nj] = __builtin_amdgcn_mfma_f32_32x32x16_bf16(               \
              af[mi][s], bf2[nj][s], acc[mi][nj], 0, 0, 0);                    \
    __builtin_amdgcn_s_setprio(0);                                             \
  } while (0)

  LOAD_TILE2(0);
  STORE_TILE2(0);
  LOAD_TILE2(BK);
  LGKM0();
  SBAR();

  for (int k0 = 0, p = 0; k0 < ID; k0 += BK, p ^= 1) {
    MFMA_HALF2(p, 0);
    if (k0 + BK < ID) STORE_TILE2(p ^ 1);
    MFMA_HALF2(p, 2);
    if (k0 + 2 * BK < ID) LOAD_TILE2(k0 + 2 * BK);
    LGKM0();
    SBAR();
  }
#undef LOAD_TILE2
#undef STORE_TILE2
#undef MFMA_HALF2

  // ---- epilogue: f32 store ----
#pragma unroll
  for (int mi = 0; mi < 4; ++mi)
#pragma unroll
    for (int nj = 0; nj < 2; ++nj)
#pragma unroll
      for (int r = 0; r < 16; ++r) {
        int row = m0 + wm * 128 + mi * 32 + fq * 4 + (r & 3) + 8 * (r >> 2);
        int col = n0 + wn * 64 + nj * 32 + fr;
        out[(size_t)(e * GT + row) * HD + col] = acc[mi][nj][r];
      }
}

extern "C" void kernel_launch(void* const* d_in, const int* in_sizes, int n_in,
                              void* d_out, int out_size, void* d_ws, size_t ws_size,
                              hipStream_t stream) {
  const float* x   = (const float*)d_in[0];
  const float* w13 = (const float*)d_in[1];
  const float* w2  = (const float*)d_in[2];
  float* out = (float*)d_out;

  // ws layout: h [0, 64 MiB) ; x_bf16 [64 MiB, 192 MiB)
  const size_t H_BYTES  = (size_t)GT * NE * ID * sizeof(__bf16);   // 64 MiB
  const size_t XB_BYTES = (size_t)GT * NE * HD * sizeof(__bf16);   // 128 MiB
  __bf16* h  = (__bf16*)d_ws;
  __bf16* xb = (__bf16*)((char*)d_ws + H_BYTES);

  if (ws_size >= H_BYTES + XB_BYTES) {
    cvt_x_bf16<<<dim3((GT * NE * (HD / 8)) / 256), dim3(256), 0, stream>>>(x, xb);
    moe_gemm1_swiglu_bA<<<dim3(1024), dim3(512), 0, stream>>>(xb, w13, h);
  } else {
    moe_gemm1_swiglu<<<dim3(ID / 64, GT / 128, NE), dim3(256), 0, stream>>>(x, w13, h);
  }
  moe_gemm2<<<dim3(1024), dim3(512), 0, stream>>>(h, w2, out);
}

// Round 14
// 559.399 us; speedup vs baseline: 1.1535x; 1.1028x over previous
//
#include <hip/hip_runtime.h>
#include <hip/hip_bf16.h>

// Problem constants (MoE grouped FFN, uniform groups)
#define NE 32      // experts
#define HD 2048    // hidden
#define ID 1024    // intermediate
#define GT 1024    // tokens per expert (T/E = 32768/32)

#define BK 64

typedef __attribute__((ext_vector_type(8))) __bf16 bf16x8;
typedef __attribute__((ext_vector_type(4))) float  f32x4;

__device__ __forceinline__ __bf16 f2b(float f) { return (__bf16)f; }

__device__ __forceinline__ bf16x8 pack8(const f32x4 a, const f32x4 b) {
  bf16x8 v;
  v[0] = f2b(a[0]); v[1] = f2b(a[1]); v[2] = f2b(a[2]); v[3] = f2b(a[3]);
  v[4] = f2b(b[0]); v[5] = f2b(b[1]); v[6] = f2b(b[2]); v[7] = f2b(b[3]);
  return v;
}

#define SBAR() __builtin_amdgcn_s_barrier()
#define LGKM0() asm volatile("s_waitcnt lgkmcnt(0)" ::: "memory")

// ---------------------------------------------------------------------------
// Prepass: x (f32, T*H) -> x_bf16 in ws. Memory-bound streaming.
// ---------------------------------------------------------------------------
__global__ __launch_bounds__(256)
void cvt_x_bf16(const float* __restrict__ x, __bf16* __restrict__ xb) {
  size_t i = ((size_t)blockIdx.x * 256 + threadIdx.x) * 8;
  f32x4 a = *reinterpret_cast<const f32x4*>(x + i);
  f32x4 b = *reinterpret_cast<const f32x4*>(x + i + 4);
  *reinterpret_cast<bf16x8*>(xb + i) = pack8(a, b);
}

// ---------------------------------------------------------------------------
// Kernel 1 (256-tile, 2-phase, 16x16x32 — R11 best, + early k+2 load issue):
// gate_up = x_e @ w13_e ; h = silu(gate)*up.
// 512 threads = 8 waves (2x4); wave owns 128 rows x 32 cols of both gate and
// up (acc = 128 f32). Loop: MFMA half1 | STORE(p^1) | issue LOAD(k+2) |
// MFMA half2 | lgkmcnt(0)+barrier.  (LOAD before the 2nd MFMA cluster gives
// the VMEM ~2500 extra cycles of cover; regs are dead post-STORE.)
// Counter-verified carried mechanics: bf16-A staging, f32-B column-walk+cvt,
// XOR swizzles (A: oct^(row&7); B: oct^((row>>1)&7)), XCD-chunked remap,
// setprio around MFMA, lgkm-only barrier (loads stay in flight).
// ---------------------------------------------------------------------------
__global__ __launch_bounds__(512, 2)
void moe_gemm1_swiglu_bA(const __bf16* __restrict__ xb,
                         const float* __restrict__ w13,
                         __bf16* __restrict__ h) {
  __shared__ __bf16 As[2][256][BK];
  __shared__ __bf16 Bg[2][128][BK];
  __shared__ __bf16 Bu[2][128][BK];

  const int t = threadIdx.x;
  const int bid  = blockIdx.x;
  const int work = (bid & 7) * 128 + (bid >> 3);
  const int e    = work >> 5;
  const int rem  = work & 31;
  const int n0   = (rem >> 2) * 128;
  const int m0   = (rem & 3) * 256;

  const __bf16* xA = xb + (size_t)(e * GT + m0) * HD;
  const float*  wB = w13 + (size_t)e * HD * (2 * ID);

  const int wid = t >> 6, lane = t & 63;
  const int wm = wid >> 2, wn = wid & 3;   // 2x4 waves: 128 rows x 32 cols
  const int fr = lane & 15, fq = lane >> 4;

  const int tb = t & 255;
  const int nq = tb & 31;
  const int ko = tb >> 5;
  const int bcol = (t < 256 ? 0 : ID) + n0 + nq * 4;
  __bf16 (*Bm)[128][BK] = (t < 256) ? Bg : Bu;

  f32x4 accg[8][2];
  f32x4 accu[8][2];
#pragma unroll
  for (int i = 0; i < 8; ++i)
#pragma unroll
    for (int j = 0; j < 2; ++j) { accg[i][j] = 0.f; accu[i][j] = 0.f; }

  bf16x8 raa[4];
  f32x4 rb[8];

#define LOAD_TILE1(K0)                                                         \
  do {                                                                         \
    _Pragma("unroll")                                                          \
    for (int i = 0; i < 4; ++i) {                                              \
      int id = i * 512 + t;                                                    \
      int koA = id & 7, m = id >> 3;                                           \
      raa[i] = *reinterpret_cast<const bf16x8*>(xA + (size_t)m * HD + (K0) + koA * 8); \
    }                                                                          \
    const float* pb = wB + (size_t)((K0) + ko * 8) * (2 * ID) + bcol;          \
    _Pragma("unroll")                                                          \
    for (int j = 0; j < 8; ++j)                                                \
      rb[j] = *reinterpret_cast<const f32x4*>(pb + (size_t)j * (2 * ID));      \
  } while (0)

#define STORE_TILE1(P)                                                         \
  do {                                                                         \
    _Pragma("unroll")                                                          \
    for (int i = 0; i < 4; ++i) {                                              \
      int id = i * 512 + t;                                                    \
      int koA = id & 7, m = id >> 3;                                           \
      *reinterpret_cast<bf16x8*>(&As[P][m][(koA ^ (m & 7)) * 8]) = raa[i];     \
    }                                                                          \
    _Pragma("unroll")                                                          \
    for (int c = 0; c < 4; ++c) {                                              \
      int row = nq * 4 + c;                                                    \
      int slot = (ko ^ ((row >> 1) & 7)) * 8;                                  \
      bf16x8 v;                                                                \
      _Pragma("unroll")                                                        \
      for (int j = 0; j < 8; ++j) v[j] = f2b(rb[j][c]);                        \
      *reinterpret_cast<bf16x8*>(&Bm[P][row][slot]) = v;                       \
    }                                                                          \
  } while (0)

#define MFMA_HALF1(P, KB)                                                      \
  do {                                                                         \
    bf16x8 af[8], bgf[2], buv[2];                                              \
    _Pragma("unroll")                                                          \
    for (int mi = 0; mi < 8; ++mi) {                                           \
      int row = wm * 128 + mi * 16 + fr;                                       \
      int oct = (fq + (KB)) ^ (row & 7);                                       \
      af[mi] = *reinterpret_cast<const bf16x8*>(&As[P][row][oct * 8]);         \
    }                                                                          \
    _Pragma("unroll")                                                          \
    for (int ni = 0; ni < 2; ++ni) {                                           \
      int row = wn * 32 + ni * 16 + fr;                                        \
      int oct = (fq + (KB)) ^ ((row >> 1) & 7);                                \
      bgf[ni] = *reinterpret_cast<const bf16x8*>(&Bg[P][row][oct * 8]);        \
      buv[ni] = *reinterpret_cast<const bf16x8*>(&Bu[P][row][oct * 8]);        \
    }                                                                          \
    __builtin_amdgcn_s_setprio(1);                                             \
    _Pragma("unroll")                                                          \
    for (int mi = 0; mi < 8; ++mi)                                             \
      _Pragma("unroll")                                                        \
      for (int ni = 0; ni < 2; ++ni) {                                         \
        accg[mi][ni] = __builtin_amdgcn_mfma_f32_16x16x32_bf16(                \
            af[mi], bgf[ni], accg[mi][ni], 0, 0, 0);                           \
        accu[mi][ni] = __builtin_amdgcn_mfma_f32_16x16x32_bf16(                \
            af[mi], buv[ni], accu[mi][ni], 0, 0, 0);                           \
      }                                                                        \
    __builtin_amdgcn_s_setprio(0);                                             \
  } while (0)

  LOAD_TILE1(0);
  STORE_TILE1(0);
  LOAD_TILE1(BK);
  LGKM0();
  SBAR();

  for (int k0 = 0, p = 0; k0 < HD; k0 += BK, p ^= 1) {
    MFMA_HALF1(p, 0);
    if (k0 + BK < HD) STORE_TILE1(p ^ 1);        // overlaps MFMA (other buffer)
    if (k0 + 2 * BK < HD) LOAD_TILE1(k0 + 2 * BK); // issue before 2nd cluster
    MFMA_HALF1(p, 4);
    LGKM0();
    SBAR();
  }
#undef LOAD_TILE1
#undef STORE_TILE1
#undef MFMA_HALF1

  // ---- epilogue: SwiGLU (in-wave), write h (bf16) ----
#pragma unroll
  for (int mi = 0; mi < 8; ++mi)
#pragma unroll
    for (int ni = 0; ni < 2; ++ni)
#pragma unroll
      for (int j = 0; j < 4; ++j) {
        int row = m0 + wm * 128 + mi * 16 + fq * 4 + j;
        int col = n0 + wn * 32 + ni * 16 + fr;
        float g = accg[mi][ni][j];
        float u = accu[mi][ni][j];
        float s = g / (1.f + __expf(-g));
        h[(size_t)(e * GT + row) * ID + col] = f2b(s * u);
      }
}

// ---------------------------------------------------------------------------
// Kernel 1 fallback (f32 A, R7 structure) — used only if ws_size too small.
// ---------------------------------------------------------------------------
__global__ __launch_bounds__(256, 2)
void moe_gemm1_swiglu(const float* __restrict__ x,
                      const float* __restrict__ w13,
                      __bf16* __restrict__ h) {
  __shared__ __bf16 As[2][128][BK];
  __shared__ __bf16 Bg[2][64][BK];
  __shared__ __bf16 Bu[2][64][BK];

  const int t  = threadIdx.x;
  const int e  = blockIdx.z;
  const int m0 = blockIdx.y * 128;
  const int n0 = blockIdx.x * 64;

  const float* xA = x   + (size_t)(e * GT + m0) * HD;
  const float* wB = w13 + (size_t)e * HD * (2 * ID);

  const int wid = t >> 6, lane = t & 63;
  const int wm = wid >> 1, wn = wid & 1;
  const int fr = lane & 15, fq = lane >> 4;

  const int tb = t & 127;
  const int nq = tb & 15;
  const int ko = tb >> 4;
  const int bcol = (t < 128 ? 0 : ID) + n0 + nq * 4;
  __bf16 (*Bm)[64][BK] = (t < 128) ? Bg : Bu;

  f32x4 accg[4][2];
  f32x4 accu[4][2];
#pragma unroll
  for (int i = 0; i < 4; ++i)
#pragma unroll
    for (int j = 0; j < 2; ++j) { accg[i][j] = 0.f; accu[i][j] = 0.f; }

  f32x4 ra[4][2];
  f32x4 rb[8];

#define LOAD_TILE1(K0)                                                         \
  do {                                                                         \
    _Pragma("unroll")                                                          \
    for (int i = 0; i < 4; ++i) {                                              \
      int id = i * 256 + t;                                                    \
      int r = id >> 3, oc = id & 7;                                            \
      const float* src = xA + (size_t)r * HD + (K0) + oc * 8;                  \
      ra[i][0] = *reinterpret_cast<const f32x4*>(src);                         \
      ra[i][1] = *reinterpret_cast<const f32x4*>(src + 4);                     \
    }                                                                          \
    const float* pb = wB + (size_t)((K0) + ko * 8) * (2 * ID) + bcol;          \
    _Pragma("unroll")                                                          \
    for (int j = 0; j < 8; ++j)                                                \
      rb[j] = *reinterpret_cast<const f32x4*>(pb + (size_t)j * (2 * ID));      \
  } while (0)

#define STORE_TILE1(P)                                                         \
  do {                                                                         \
    _Pragma("unroll")                                                          \
    for (int i = 0; i < 4; ++i) {                                              \
      int id = i * 256 + t;                                                    \
      int r = id >> 3, oc = id & 7;                                            \
      *reinterpret_cast<bf16x8*>(&As[P][r][(oc ^ (r & 7)) * 8]) =              \
          pack8(ra[i][0], ra[i][1]);                                           \
    }                                                                          \
    _Pragma("unroll")                                                          \
    for (int c = 0; c < 4; ++c) {                                              \
      int row = nq * 4 + c;                                                    \
      int slot = (ko ^ ((row >> 1) & 7)) * 8;                                  \
      bf16x8 v;                                                                \
      _Pragma("unroll")                                                        \
      for (int j = 0; j < 8; ++j) v[j] = f2b(rb[j][c]);                        \
      *reinterpret_cast<bf16x8*>(&Bm[P][row][slot]) = v;                       \
    }                                                                          \
  } while (0)

#define MFMA_HALF1(P, KB)                                                      \
  do {                                                                         \
    bf16x8 af[4], bgf[2], buf2[2];                                             \
    _Pragma("unroll")                                                          \
    for (int mi = 0; mi < 4; ++mi) {                                           \
      int row = wm * 64 + mi * 16 + fr;                                        \
      int oct = (fq + (KB)) ^ (row & 7);                                       \
      af[mi] = *reinterpret_cast<const bf16x8*>(&As[P][row][oct * 8]);         \
    }                                                                          \
    _Pragma("unroll")                                                          \
    for (int ni = 0; ni < 2; ++ni) {                                           \
      int row = wn * 32 + ni * 16 + fr;                                        \
      int oct = (fq + (KB)) ^ ((row >> 1) & 7);                                \
      bgf[ni]  = *reinterpret_cast<const bf16x8*>(&Bg[P][row][oct * 8]);       \
      buf2[ni] = *reinterpret_cast<const bf16x8*>(&Bu[P][row][oct * 8]);       \
    }                                                                          \
    __builtin_amdgcn_s_setprio(1);                                             \
    _Pragma("unroll")                                                          \
    for (int mi = 0; mi < 4; ++mi)                                             \
      _Pragma("unroll")                                                        \
      for (int ni = 0; ni < 2; ++ni) {                                         \
        accg[mi][ni] = __builtin_amdgcn_mfma_f32_16x16x32_bf16(                \
            af[mi], bgf[ni], accg[mi][ni], 0, 0, 0);                           \
        accu[mi][ni] = __builtin_amdgcn_mfma_f32_16x16x32_bf16(                \
            af[mi], buf2[ni], accu[mi][ni], 0, 0, 0);                          \
      }                                                                        \
    __builtin_amdgcn_s_setprio(0);                                             \
  } while (0)

  LOAD_TILE1(0);
  STORE_TILE1(0);
  LOAD_TILE1(BK);
  LGKM0();
  SBAR();

  for (int k0 = 0, p = 0; k0 < HD; k0 += BK, p ^= 1) {
    MFMA_HALF1(p, 0);
    if (k0 + BK < HD) STORE_TILE1(p ^ 1);
    MFMA_HALF1(p, 4);
    if (k0 + 2 * BK < HD) LOAD_TILE1(k0 + 2 * BK);
    LGKM0();
    SBAR();
  }
#undef LOAD_TILE1
#undef STORE_TILE1
#undef MFMA_HALF1

#pragma unroll
  for (int mi = 0; mi < 4; ++mi)
#pragma unroll
    for (int ni = 0; ni < 2; ++ni)
#pragma unroll
      for (int j = 0; j < 4; ++j) {
        int row = m0 + wm * 64 + mi * 16 + fq * 4 + j;
        int col = n0 + wn * 32 + ni * 16 + fr;
        float g = accg[mi][ni][j];
        float u = accu[mi][ni][j];
        float s = g / (1.f + __expf(-g));
        h[(size_t)(e * GT + row) * ID + col] = f2b(s * u);
      }
}

// ---------------------------------------------------------------------------
// Kernel 2 (256x256 tile, 2-phase, 16x16x32 — R11 best, + early load issue):
// out = h @ w2_e. 512 threads = 8 waves (2x4); wave owns 128 x 64 (acc 128).
// ---------------------------------------------------------------------------
__global__ __launch_bounds__(512, 2)
void moe_gemm2(const __bf16* __restrict__ h,
               const float* __restrict__ w2,
               float* __restrict__ out) {
  __shared__ __bf16 As[2][256][BK];
  __shared__ __bf16 Bs[2][256][BK];

  const int t = threadIdx.x;
  const int bid  = blockIdx.x;
  const int work = (bid & 7) * 128 + (bid >> 3);
  const int e    = work >> 5;
  const int rem  = work & 31;
  const int n0   = (rem >> 2) * 256;
  const int m0   = (rem & 3) * 256;

  const __bf16* hA = h  + (size_t)(e * GT + m0) * ID;
  const float*  wB = w2 + (size_t)e * ID * HD;

  const int wid = t >> 6, lane = t & 63;
  const int wm = wid >> 2, wn = wid & 3;
  const int fr = lane & 15, fq = lane >> 4;

  const int nq = t & 63;
  const int ko = t >> 6;

  f32x4 acc[8][4];
#pragma unroll
  for (int i = 0; i < 8; ++i)
#pragma unroll
    for (int j = 0; j < 4; ++j) acc[i][j] = 0.f;

  bf16x8 raa[4];
  f32x4 rb[8];

#define LOAD_TILE2(K0)                                                         \
  do {                                                                         \
    _Pragma("unroll")                                                          \
    for (int i = 0; i < 4; ++i) {                                              \
      int id = i * 512 + t;                                                    \
      int koA = id & 7, m = id >> 3;                                           \
      raa[i] = *reinterpret_cast<const bf16x8*>(hA + (size_t)m * ID + (K0) + koA * 8); \
    }                                                                          \
    const float* pg = wB + (size_t)((K0) + ko * 8) * HD + (n0 + nq * 4);       \
    _Pragma("unroll")                                                          \
    for (int j = 0; j < 8; ++j)                                                \
      rb[j] = *reinterpret_cast<const f32x4*>(pg + (size_t)j * HD);            \
  } while (0)

#define STORE_TILE2(P)                                                         \
  do {                                                                         \
    _Pragma("unroll")                                                          \
    for (int i = 0; i < 4; ++i) {                                              \
      int id = i * 512 + t;                                                    \
      int koA = id & 7, m = id >> 3;                                           \
      *reinterpret_cast<bf16x8*>(&As[P][m][(koA ^ (m & 7)) * 8]) = raa[i];     \
    }                                                                          \
    _Pragma("unroll")                                                          \
    for (int c = 0; c < 4; ++c) {                                              \
      int row = nq * 4 + c;                                                    \
      int slot = (ko ^ ((row >> 1) & 7)) * 8;                                  \
      bf16x8 v;                                                                \
      _Pragma("unroll")                                                        \
      for (int j = 0; j < 8; ++j) v[j] = f2b(rb[j][c]);                        \
      *reinterpret_cast<bf16x8*>(&Bs[P][row][slot]) = v;                       \
    }                                                                          \
  } while (0)

#define MFMA_HALF2(P, KB)                                                      \
  do {                                                                         \
    bf16x8 af[8], bf[4];                                                       \
    _Pragma("unroll")                                                          \
    for (int mi = 0; mi < 8; ++mi) {                                           \
      int row = wm * 128 + mi * 16 + fr;                                       \
      int oct = (fq + (KB)) ^ (row & 7);                                       \
      af[mi] = *reinterpret_cast<const bf16x8*>(&As[P][row][oct * 8]);         \
    }                                                                          \
    _Pragma("unroll")                                                          \
    for (int ni = 0; ni < 4; ++ni) {                                           \
      int row = wn * 64 + ni * 16 + fr;                                        \
      int oct = (fq + (KB)) ^ ((row >> 1) & 7);                                \
      bf[ni] = *reinterpret_cast<const bf16x8*>(&Bs[P][row][oct * 8]);         \
    }                                                                          \
    __builtin_amdgcn_s_setprio(1);                                             \
    _Pragma("unroll")                                                          \
    for (int mi = 0; mi < 8; ++mi)                                             \
      _Pragma("unroll")                                                        \
      for (int ni = 0; ni < 4; ++ni)                                           \
        acc[mi][ni] = __builtin_amdgcn_mfma_f32_16x16x32_bf16(                 \
            af[mi], bf[ni], acc[mi][ni], 0, 0, 0);                             \
    __builtin_amdgcn_s_setprio(0);                                             \
  } while (0)

  LOAD_TILE2(0);
  STORE_TILE2(0);
  LOAD_TILE2(BK);
  LGKM0();
  SBAR();

  for (int k0 = 0, p = 0; k0 < ID; k0 += BK, p ^= 1) {
    MFMA_HALF2(p, 0);
    if (k0 + BK < ID) STORE_TILE2(p ^ 1);
    if (k0 + 2 * BK < ID) LOAD_TILE2(k0 + 2 * BK);
    MFMA_HALF2(p, 4);
    LGKM0();
    SBAR();
  }
#undef LOAD_TILE2
#undef STORE_TILE2
#undef MFMA_HALF2

#pragma unroll
  for (int mi = 0; mi < 8; ++mi)
#pragma unroll
    for (int ni = 0; ni < 4; ++ni)
#pragma unroll
      for (int j = 0; j < 4; ++j) {
        int row = m0 + wm * 128 + mi * 16 + fq * 4 + j;
        int col = n0 + wn * 64 + ni * 16 + fr;
        out[(size_t)(e * GT + row) * HD + col] = acc[mi][ni][j];
      }
}

extern "C" void kernel_launch(void* const* d_in, const int* in_sizes, int n_in,
                              void* d_out, int out_size, void* d_ws, size_t ws_size,
                              hipStream_t stream) {
  const float* x   = (const float*)d_in[0];
  const float* w13 = (const float*)d_in[1];
  const float* w2  = (const float*)d_in[2];
  float* out = (float*)d_out;

  // ws layout: h [0, 64 MiB) ; x_bf16 [64 MiB, 192 MiB)
  const size_t H_BYTES  = (size_t)GT * NE * ID * sizeof(__bf16);   // 64 MiB
  const size_t XB_BYTES = (size_t)GT * NE * HD * sizeof(__bf16);   // 128 MiB
  __bf16* h  = (__bf16*)d_ws;
  __bf16* xb = (__bf16*)((char*)d_ws + H_BYTES);

  if (ws_size >= H_BYTES + XB_BYTES) {
    cvt_x_bf16<<<dim3((GT * NE * (HD / 8)) / 256), dim3(256), 0, stream>>>(x, xb);
    moe_gemm1_swiglu_bA<<<dim3(1024), dim3(512), 0, stream>>>(xb, w13, h);
  } else {
    moe_gemm1_swiglu<<<dim3(ID / 64, GT / 128, NE), dim3(256), 0, stream>>>(x, w13, h);
  }
  moe_gemm2<<<dim3(1024), dim3(512), 0, stream>>>(h, w2, out);
}